// Round 1
// baseline (590.973 us; speedup 1.0000x reference)
//
#include <hip/hip_runtime.h>
#include <stdint.h>

// QLinear HQQ 4-bit: out = x @ dequant(W_q).T + bias
// M=8192 tokens, N=4096 out features, K=4096 in features, group=64 along K.
//
// R3: replace the 128x128 2-barrier GEMM (781 TF, MfmaUtil 36% -- the m97
// drain-stall signature) with a 256x256/BK32 deep-pipelined schedule:
//  - 3-slot LDS ring (96 KB), stage tile T+2 while computing tile T
//  - counted s_waitcnt vmcnt(4) + RAW s_barrier (loads stay in flight
//    across barriers; vmcnt never drains to 0 in the main loop)
//  - s_setprio(1) around each 16-MFMA cluster
//  - same verified granule XOR-swizzle (phys = logical ^ ((row>>1)&3)),
//    applied on the pre-swizzled GLOBAL source (global_load_lds writes
//    linearly), conflict-free ds_read_b128 fragment reads.
// Also fuse the two prep kernels (x->f16 cvt, W dequant) into one launch.

typedef __attribute__((ext_vector_type(8))) _Float16 half8;
typedef __attribute__((ext_vector_type(4))) float f32x4;

#define M_DIM 8192
#define N_DIM 4096
#define K_DIM 4096

__device__ __forceinline__ void async16(const void* g, void* l) {
  // 16B/lane direct global->LDS. LDS dest is wave-uniform base + lane*16.
  __builtin_amdgcn_global_load_lds(
      (const __attribute__((address_space(1))) void*)g,
      (__attribute__((address_space(3))) void*)l,
      16, 0, 0);
}

// ---------------- stage 1 (fused): x fp32->f16  +  W_q dequant->f16 --------
// blocks [0, 16384): convert x (8 fp32 -> 8 f16 per thread)
// blocks [16384, 24576): dequant W -> f16 [N][K]
__global__ __launch_bounds__(256) void prep(
    const float* __restrict__ x, const int* __restrict__ Wq,
    const float* __restrict__ scale, const float* __restrict__ zero,
    _Float16* __restrict__ xh, _Float16* __restrict__ wh) {
  const int b = blockIdx.x;
  if (b < 16384) {
    const size_t i = ((size_t)b * 256 + threadIdx.x) * 8;
    f32x4 a = *(const f32x4*)(x + i);
    f32x4 c = *(const f32x4*)(x + i + 4);
    half8 h;
    h[0] = (_Float16)a[0]; h[1] = (_Float16)a[1];
    h[2] = (_Float16)a[2]; h[3] = (_Float16)a[3];
    h[4] = (_Float16)c[0]; h[5] = (_Float16)c[1];
    h[6] = (_Float16)c[2]; h[7] = (_Float16)c[3];
    *(half8*)(xh + i) = h;
  } else {
    const int idx = (b - 16384) * 256 + threadIdx.x;  // 0..2097151, 8 elems
    const int o  = idx >> 9;                          // row 0..4095
    const int kb = (idx & 511) << 3;                  // col start, step 8
    const int g  = (o << 6) + (kb >> 6);              // group id
    const int j  = kb & 63;
    const bool hi = (o < 2048);
    const int* src = Wq + (size_t)(hi ? g : g - 131072) * 64 + j;
    const int4 v0 = *(const int4*)src;
    const int4 v1 = *(const int4*)(src + 4);
    const float s  = scale[g];
    const float nz = -zero[g] * s;                    // (nib - z)*s = nib*s + nz
    int raw[8] = {v0.x, v0.y, v0.z, v0.w, v1.x, v1.y, v1.z, v1.w};
    half8 h;
#pragma unroll
    for (int r = 0; r < 8; ++r) {
      const int nib = hi ? ((raw[r] >> 4) & 0xF) : (raw[r] & 0xF);
      h[r] = (_Float16)((float)nib * s + nz);
    }
    *(half8*)(wh + (size_t)o * K_DIM + kb) = h;
  }
}

// ---------------- stage 2: deep-pipelined f16 MFMA GEMM-BT -----------------
// C[m][n] = sum_k A[m][k]*B[n][k] + bias[n].  A:[M][K] f16, B:[N][K] f16.
// Block tile 256x256, BK=32, 512 threads = 8 waves (2M x 4N), each wave a
// 128x64 sub-tile = 8x4 grid of 16x16x32 MFMAs.  LDS: 3 slots x (16KB A +
// 16KB B) ring.  Schedule per tile T: issue stage(T+2) -> reads+MFMA from
// slot T%3 -> vmcnt(4) (stage(T+1) landed, stage(T+2) in flight) -> barrier.
__global__ __launch_bounds__(512, 2) void gemm_f16_deep(
    const _Float16* __restrict__ A, const _Float16* __restrict__ B,
    const float* __restrict__ bias, float* __restrict__ C) {
  __shared__ _Float16 As[3 * 8192];   // 48 KB: 3 slots of 256 rows x 32 halfs
  __shared__ _Float16 Bs[3 * 8192];   // 48 KB

  const int tid  = threadIdx.x;
  const int wave = tid >> 6;
  const int lane = tid & 63;
  const int quad = lane >> 4;
  const int l16  = lane & 15;
  const int wm   = wave >> 2;          // 0..1  (M half)
  const int wn   = wave & 3;           // 0..3  (N quarter)

  // XCD-aware swizzle: 512 blocks, 8 XCDs -> 64 contiguous per XCD.
  const int bid = blockIdx.x;
  const int swb = (bid & 7) * 64 + (bid >> 3);
  const int m0 = (swb >> 4) * 256;     // 32 row-blocks
  const int n0 = (swb & 15) * 256;     // 16 col-blocks

  // staging: thread t's 16B lands at LDS byte t*16 (row t/4, phys granule t%4).
  // Fetch the LOGICAL granule (t%4) ^ ((row>>1)&3) so reads can un-swizzle.
  const int srow = tid >> 2;                          // 0..127
  const int sg   = (((tid & 3) ^ ((srow >> 1) & 3)) << 3);
  const _Float16* gA0 = A + (size_t)(m0 + srow) * K_DIM + sg;      // rows 0..127
  const _Float16* gA1 = gA0 + (size_t)128 * K_DIM;                 // rows 128..255
  const _Float16* gB0 = B + (size_t)(n0 + srow) * K_DIM + sg;
  const _Float16* gB1 = gB0 + (size_t)128 * K_DIM;
  const int wst = wave * 512;          // wave-uniform stage offset (halfs)

  // fragment reads: un-swizzle with the same row-derived XOR
  const int fro  = ((quad ^ ((l16 >> 1) & 3)) << 3);  // granule offset (halfs)
  const int arow = wm * 128 + l16;                    // + i*16
  const int brow = wn * 64 + l16;                     // + j*16

  f32x4 acc[8][4] = {};

  // slot ring offsets (halfs): read slot, next slot, write slot
  int sR = 0, sN = 8192, sW = 16384;

  // prologue: stage tiles 0 and 1; wait tile 0 only (tile 1 stays in flight)
  async16(gA0,      As + sR + wst);
  async16(gA1,      As + sR + 4096 + wst);
  async16(gB0,      Bs + sR + wst);
  async16(gB1,      Bs + sR + 4096 + wst);
  async16(gA0 + 32, As + sN + wst);
  async16(gA1 + 32, As + sN + 4096 + wst);
  async16(gB0 + 32, Bs + sN + wst);
  async16(gB1 + 32, Bs + sN + 4096 + wst);
  asm volatile("s_waitcnt vmcnt(4)" ::: "memory");
  __builtin_amdgcn_s_barrier();

  const int NT = K_DIM / 32;           // 128
#pragma unroll 1
  for (int T = 0; T < NT; ++T) {
    if (T + 2 < NT) {                  // stage tile T+2 into the write slot
      const int kk = (T + 2) * 32;
      async16(gA0 + kk, As + sW + wst);
      async16(gA1 + kk, As + sW + 4096 + wst);
      async16(gB0 + kk, Bs + sW + wst);
      async16(gB1 + kk, Bs + sW + 4096 + wst);
    }

    const _Float16* Ab = As + sR;
    const _Float16* Bb = Bs + sR;
    half8 aF[4], bF[4];
#pragma unroll
    for (int j = 0; j < 4; ++j)
      bF[j] = *(const half8*)(Bb + (brow + j * 16) * 32 + fro);
#pragma unroll
    for (int i = 0; i < 4; ++i)
      aF[i] = *(const half8*)(Ab + (arow + i * 16) * 32 + fro);

    __builtin_amdgcn_s_setprio(1);
#pragma unroll
    for (int i = 0; i < 4; ++i)
#pragma unroll
      for (int j = 0; j < 4; ++j)
        acc[i][j] = __builtin_amdgcn_mfma_f32_16x16x32_f16(aF[i], bF[j],
                                                           acc[i][j], 0, 0, 0);
    __builtin_amdgcn_s_setprio(0);

#pragma unroll
    for (int i = 0; i < 4; ++i)
      aF[i] = *(const half8*)(Ab + (arow + 64 + i * 16) * 32 + fro);

    __builtin_amdgcn_s_setprio(1);
#pragma unroll
    for (int i = 0; i < 4; ++i)
#pragma unroll
      for (int j = 0; j < 4; ++j)
        acc[i + 4][j] = __builtin_amdgcn_mfma_f32_16x16x32_f16(aF[i], bF[j],
                                                               acc[i + 4][j],
                                                               0, 0, 0);
    __builtin_amdgcn_s_setprio(0);

    if (T + 2 < NT) {
      // stage(T+1) landed (issued a full tile ago); stage(T+2) in flight
      asm volatile("s_waitcnt vmcnt(4)" ::: "memory");
      __builtin_amdgcn_s_barrier();
    } else if (T + 1 < NT) {
      asm volatile("s_waitcnt vmcnt(0)" ::: "memory");
      __builtin_amdgcn_s_barrier();
    }
    const int t = sR; sR = sN; sN = sW; sW = t;   // rotate ring
  }

  // epilogue: D row = quad*4 + reg, col = l16
#pragma unroll
  for (int j = 0; j < 4; ++j) {
    const int n = n0 + wn * 64 + j * 16 + l16;
    const float bv = bias[n];
#pragma unroll
    for (int i = 0; i < 8; ++i) {
      const int m = m0 + wm * 128 + i * 16 + quad * 4;
      float* p = C + (size_t)m * N_DIM + n;
      f32x4 v = acc[i][j];
      p[0 * N_DIM] = v[0] + bv;
      p[1 * N_DIM] = v[1] + bv;
      p[2 * N_DIM] = v[2] + bv;
      p[3 * N_DIM] = v[3] + bv;
    }
  }
}

// ---------------- fallback: fused fp32 GEMM, no workspace ----------------
__global__ __launch_bounds__(256) void gemm_fp32_fallback(
    const float* __restrict__ x, const int* __restrict__ Wq,
    const float* __restrict__ scale, const float* __restrict__ zero,
    const float* __restrict__ bias, float* __restrict__ C) {
  __shared__ float As[64][16];
  __shared__ float Bs[64][16];
  const int tid = threadIdx.x;
  const int m0 = blockIdx.y * 64;
  const int n0 = blockIdx.x * 64;
  const int tx = tid & 15;
  const int ty = tid >> 4;
  const int lr = tid >> 2;
  const int lc = (tid & 3) << 2;

  float acc[4][4] = {};

  for (int k0 = 0; k0 < K_DIM; k0 += 16) {
    __syncthreads();
    *(f32x4*)&As[lr][lc] = *(const f32x4*)(x + (size_t)(m0 + lr) * K_DIM + k0 + lc);
    {
      const int o = n0 + lr;
      const int k = k0 + lc;
      const int g = (o << 6) + (k >> 6);
      const bool hi = (o < 2048);
      const int* src = Wq + (size_t)(hi ? g : g - 131072) * 64 + (k & 63);
      const int4 v = *(const int4*)src;
      const float s = scale[g];
      const float nz = -zero[g] * s;
      f32x4 b;
      if (hi) {
        b[0] = (float)((v.x >> 4) & 0xF) * s + nz;
        b[1] = (float)((v.y >> 4) & 0xF) * s + nz;
        b[2] = (float)((v.z >> 4) & 0xF) * s + nz;
        b[3] = (float)((v.w >> 4) & 0xF) * s + nz;
      } else {
        b[0] = (float)(v.x & 0xF) * s + nz;
        b[1] = (float)(v.y & 0xF) * s + nz;
        b[2] = (float)(v.z & 0xF) * s + nz;
        b[3] = (float)(v.w & 0xF) * s + nz;
      }
      *(f32x4*)&Bs[lr][lc] = b;
    }
    __syncthreads();
#pragma unroll
    for (int kk = 0; kk < 16; ++kk) {
      float a[4], b[4];
#pragma unroll
      for (int r = 0; r < 4; ++r) a[r] = As[ty * 4 + r][kk];
#pragma unroll
      for (int c = 0; c < 4; ++c) b[c] = Bs[tx * 4 + c][kk];
#pragma unroll
      for (int r = 0; r < 4; ++r)
#pragma unroll
        for (int c = 0; c < 4; ++c) acc[r][c] += a[r] * b[c];
    }
  }
#pragma unroll
  for (int r = 0; r < 4; ++r)
#pragma unroll
    for (int c = 0; c < 4; ++c) {
      const int n = n0 + tx * 4 + c;
      C[(size_t)(m0 + ty * 4 + r) * N_DIM + n] = acc[r][c] + bias[n];
    }
}

extern "C" void kernel_launch(void* const* d_in, const int* in_sizes, int n_in,
                              void* d_out, int out_size, void* d_ws, size_t ws_size,
                              hipStream_t stream) {
  const float* x     = (const float*)d_in[0];
  const int*   Wq    = (const int*)d_in[1];
  const float* scale = (const float*)d_in[2];
  const float* zero  = (const float*)d_in[3];
  const float* bias  = (const float*)d_in[4];
  float* out = (float*)d_out;

  const size_t xh_bytes = (size_t)M_DIM * K_DIM * 2;  // 64 MB
  const size_t wh_bytes = (size_t)N_DIM * K_DIM * 2;  // 32 MB

  if (ws_size >= xh_bytes + wh_bytes) {
    _Float16* xh = (_Float16*)d_ws;
    _Float16* wh = (_Float16*)((char*)d_ws + xh_bytes);
    prep<<<16384 + 8192, 256, 0, stream>>>(x, Wq, scale, zero, xh, wh);
    gemm_f16_deep<<<(M_DIM / 256) * (N_DIM / 256), 512, 0, stream>>>(xh, wh, bias, out);
  } else {
    dim3 grid(N_DIM / 64, M_DIM / 64);    // (64, 128)
    gemm_fp32_fallback<<<grid, 256, 0, stream>>>(x, Wq, scale, zero, bias, out);
  }
}

// Round 2
// 517.317 us; speedup vs baseline: 1.1424x; 1.1424x over previous
//
#include <hip/hip_runtime.h>
#include <stdint.h>

// QLinear HQQ 4-bit: out = x @ dequant(W_q).T + bias
// M=8192 tokens, N=4096 out features, K=4096 in features, group=64 along K.
//
// R4: fix R3's coarse-split regression (m196 failure mode). Keep the
// race-free 3-slot LDS ring + counted vmcnt, but restructure each K-tile
// (BK=32) into TWO fine phases in the proven m201 style:
//   P0: {8 ds_read_b128 (aF_low + bF) | stage T+2 A-halves}
//       -> s_barrier -> lgkmcnt(0) -> setprio(1) -> 16 MFMA -> setprio(0) -> s_barrier
//   P1: {4 ds_read_b128 (aF_high)    | stage T+2 B-halves -> vmcnt(4)}
//       -> s_barrier -> lgkmcnt(0) -> setprio(1) -> 16 MFMA -> setprio(0) -> s_barrier
// vmcnt(4) = tile T+2's 4 in-flight loads; guarantees tile T+1 landed.
// Ring slots compile-time via manual unroll-by-3. Swizzle unchanged from
// R2 (verified 0 bank conflicts): phys granule = logical ^ ((row>>1)&3),
// applied on the pre-swizzled GLOBAL source (global_load_lds is linear).

typedef __attribute__((ext_vector_type(8))) _Float16 half8;
typedef __attribute__((ext_vector_type(4))) float f32x4;

#define M_DIM 8192
#define N_DIM 4096
#define K_DIM 4096

__device__ __forceinline__ void async16(const void* g, void* l) {
  // 16B/lane direct global->LDS. LDS dest is wave-uniform base + lane*16.
  __builtin_amdgcn_global_load_lds(
      (const __attribute__((address_space(1))) void*)g,
      (__attribute__((address_space(3))) void*)l,
      16, 0, 0);
}

// ---------------- stage 1 (fused): x fp32->f16  +  W_q dequant->f16 --------
__global__ __launch_bounds__(256) void prep(
    const float* __restrict__ x, const int* __restrict__ Wq,
    const float* __restrict__ scale, const float* __restrict__ zero,
    _Float16* __restrict__ xh, _Float16* __restrict__ wh) {
  const int b = blockIdx.x;
  if (b < 16384) {
    const size_t i = ((size_t)b * 256 + threadIdx.x) * 8;
    f32x4 a = *(const f32x4*)(x + i);
    f32x4 c = *(const f32x4*)(x + i + 4);
    half8 h;
    h[0] = (_Float16)a[0]; h[1] = (_Float16)a[1];
    h[2] = (_Float16)a[2]; h[3] = (_Float16)a[3];
    h[4] = (_Float16)c[0]; h[5] = (_Float16)c[1];
    h[6] = (_Float16)c[2]; h[7] = (_Float16)c[3];
    *(half8*)(xh + i) = h;
  } else {
    const int idx = (b - 16384) * 256 + threadIdx.x;  // 0..2097151, 8 elems
    const int o  = idx >> 9;                          // row 0..4095
    const int kb = (idx & 511) << 3;                  // col start, step 8
    const int g  = (o << 6) + (kb >> 6);              // group id
    const int j  = kb & 63;
    const bool hi = (o < 2048);
    const int* src = Wq + (size_t)(hi ? g : g - 131072) * 64 + j;
    const int4 v0 = *(const int4*)src;
    const int4 v1 = *(const int4*)(src + 4);
    const float s  = scale[g];
    const float nz = -zero[g] * s;                    // (nib - z)*s = nib*s + nz
    int raw[8] = {v0.x, v0.y, v0.z, v0.w, v1.x, v1.y, v1.z, v1.w};
    half8 h;
#pragma unroll
    for (int r = 0; r < 8; ++r) {
      const int nib = hi ? ((raw[r] >> 4) & 0xF) : (raw[r] & 0xF);
      h[r] = (_Float16)((float)nib * s + nz);
    }
    *(half8*)(wh + (size_t)o * K_DIM + kb) = h;
  }
}

// ---------------- stage 2: fine-phased f16 MFMA GEMM-BT --------------------
// Block tile 256x256, BK=32, 512 threads = 8 waves (2M x 4N), each wave a
// 128x64 sub-tile = 8x4 fragments of 16x16x32.  LDS: 3-slot ring, 96 KB.
__global__ __launch_bounds__(512, 2) void gemm_f16_fine(
    const _Float16* __restrict__ A, const _Float16* __restrict__ B,
    const float* __restrict__ bias, float* __restrict__ C) {
  __shared__ _Float16 As[3 * 8192];   // 48 KB: 3 slots of [256 rows][32 halfs]
  __shared__ _Float16 Bs[3 * 8192];   // 48 KB

  const int tid  = threadIdx.x;
  const int wave = tid >> 6;
  const int lane = tid & 63;
  const int quad = lane >> 4;
  const int l16  = lane & 15;
  const int wm   = wave >> 2;          // 0..1  (M half)
  const int wn   = wave & 3;           // 0..3  (N quarter)

  // XCD-aware swizzle: 512 blocks, 8 XCDs -> 64 contiguous per XCD.
  const int bid = blockIdx.x;
  const int swb = (bid & 7) * 64 + (bid >> 3);
  const int m0 = (swb >> 4) * 256;     // 32 row-blocks
  const int n0 = (swb & 15) * 256;     // 16 col-blocks

  // staging: thread t's 16B lands at LDS linear granule t (row t>>2, phys
  // granule t&3). Fetch LOGICAL granule (t&3)^((row>>1)&3) from global.
  const int srow = tid >> 2;                          // 0..127
  const int sg   = (((tid & 3) ^ ((tid >> 3) & 3)) << 3);
  const _Float16* gA0 = A + (size_t)(m0 + srow) * K_DIM + sg;      // rows 0..127
  const _Float16* gA1 = gA0 + (size_t)128 * K_DIM;                 // rows 128..255
  const _Float16* gB0 = B + (size_t)(n0 + srow) * K_DIM + sg;
  const _Float16* gB1 = gB0 + (size_t)128 * K_DIM;
  const int wst = wave * 512;          // wave-uniform stage offset (halfs)

  // fragment reads: un-swizzle with the same row-derived XOR
  const int fro  = ((quad ^ ((l16 >> 1) & 3)) << 3);  // granule offset (halfs)
  const int arow = wm * 128 + l16;                    // + i*16 (+64 for high)
  const int brow = wn * 64 + l16;                     // + j*16

  f32x4 acc[8][4] = {};

  const int NT = K_DIM / 32;           // 128

  // prologue: stage tile 0 -> slot 0, tile 1 -> slot 1; wait tile 0 only.
  async16(gA0,      As + wst);
  async16(gA1,      As + 4096 + wst);
  async16(gB0,      Bs + wst);
  async16(gB1,      Bs + 4096 + wst);
  async16(gA0 + 32, As + 8192 + wst);
  async16(gA1 + 32, As + 8192 + 4096 + wst);
  async16(gB0 + 32, Bs + 8192 + wst);
  async16(gB1 + 32, Bs + 8192 + 4096 + wst);
  asm volatile("s_waitcnt vmcnt(4)" ::: "memory");
  __builtin_amdgcn_s_barrier();

// One K-tile = two fine phases. SR/SW are compile-time slot offsets (halfs).
#define KSTEP(SR, SW, T)                                                     \
  {                                                                          \
    half8 aF[4], bF[4];                                                      \
    /* ---- P0: read aF_low + bF, stage T+2 A-halves ---- */                 \
    _Pragma("unroll") for (int j = 0; j < 4; ++j)                            \
      bF[j] = *(const half8*)(Bs + (SR) + (brow + j * 16) * 32 + fro);       \
    _Pragma("unroll") for (int i = 0; i < 4; ++i)                            \
      aF[i] = *(const half8*)(As + (SR) + (arow + i * 16) * 32 + fro);       \
    if ((T) + 2 < NT) {                                                      \
      const int kk = ((T) + 2) * 32;                                         \
      async16(gA0 + kk, As + (SW) + wst);                                    \
      async16(gA1 + kk, As + (SW) + 4096 + wst);                             \
    }                                                                        \
    __builtin_amdgcn_s_barrier();                                            \
    asm volatile("s_waitcnt lgkmcnt(0)" ::: "memory");                       \
    __builtin_amdgcn_s_setprio(1);                                           \
    _Pragma("unroll") for (int i = 0; i < 4; ++i)                            \
      _Pragma("unroll") for (int j = 0; j < 4; ++j)                          \
        acc[i][j] = __builtin_amdgcn_mfma_f32_16x16x32_f16(                  \
            aF[i], bF[j], acc[i][j], 0, 0, 0);                               \
    __builtin_amdgcn_s_setprio(0);                                           \
    __builtin_amdgcn_s_barrier();                                            \
    /* ---- P1: read aF_high, stage T+2 B-halves, counted vmcnt ---- */      \
    _Pragma("unroll") for (int i = 0; i < 4; ++i)                            \
      aF[i] = *(const half8*)(As + (SR) + (arow + 64 + i * 16) * 32 + fro);  \
    if ((T) + 2 < NT) {                                                      \
      const int kk = ((T) + 2) * 32;                                         \
      async16(gB0 + kk, Bs + (SW) + wst);                                    \
      async16(gB1 + kk, Bs + (SW) + 4096 + wst);                             \
      asm volatile("s_waitcnt vmcnt(4)" ::: "memory");                       \
    } else {                                                                 \
      asm volatile("s_waitcnt vmcnt(0)" ::: "memory");                       \
    }                                                                        \
    __builtin_amdgcn_s_barrier();                                            \
    asm volatile("s_waitcnt lgkmcnt(0)" ::: "memory");                       \
    __builtin_amdgcn_s_setprio(1);                                           \
    _Pragma("unroll") for (int i = 0; i < 4; ++i)                            \
      _Pragma("unroll") for (int j = 0; j < 4; ++j)                          \
        acc[i + 4][j] = __builtin_amdgcn_mfma_f32_16x16x32_f16(              \
            aF[i], bF[j], acc[i + 4][j], 0, 0, 0);                           \
    __builtin_amdgcn_s_setprio(0);                                           \
    __builtin_amdgcn_s_barrier();                                            \
  }

  // main loop: ring period 3, slots compile-time.  126 = 42*3; tail = 2.
  for (int T = 0; T < 126; T += 3) {
    KSTEP(0,     16384, T)
    KSTEP(8192,  0,     T + 1)
    KSTEP(16384, 8192,  T + 2)
  }
  KSTEP(0,    16384, 126)
  KSTEP(8192, 0,     127)
#undef KSTEP

  // epilogue: D row = quad*4 + reg, col = l16
#pragma unroll
  for (int j = 0; j < 4; ++j) {
    const int n = n0 + wn * 64 + j * 16 + l16;
    const float bv = bias[n];
#pragma unroll
    for (int i = 0; i < 8; ++i) {
      const int m = m0 + wm * 128 + i * 16 + quad * 4;
      float* p = C + (size_t)m * N_DIM + n;
      f32x4 v = acc[i][j];
      p[0 * N_DIM] = v[0] + bv;
      p[1 * N_DIM] = v[1] + bv;
      p[2 * N_DIM] = v[2] + bv;
      p[3 * N_DIM] = v[3] + bv;
    }
  }
}

// ---------------- fallback: fused fp32 GEMM, no workspace ----------------
__global__ __launch_bounds__(256) void gemm_fp32_fallback(
    const float* __restrict__ x, const int* __restrict__ Wq,
    const float* __restrict__ scale, const float* __restrict__ zero,
    const float* __restrict__ bias, float* __restrict__ C) {
  __shared__ float As[64][16];
  __shared__ float Bs[64][16];
  const int tid = threadIdx.x;
  const int m0 = blockIdx.y * 64;
  const int n0 = blockIdx.x * 64;
  const int tx = tid & 15;
  const int ty = tid >> 4;
  const int lr = tid >> 2;
  const int lc = (tid & 3) << 2;

  float acc[4][4] = {};

  for (int k0 = 0; k0 < K_DIM; k0 += 16) {
    __syncthreads();
    *(f32x4*)&As[lr][lc] = *(const f32x4*)(x + (size_t)(m0 + lr) * K_DIM + k0 + lc);
    {
      const int o = n0 + lr;
      const int k = k0 + lc;
      const int g = (o << 6) + (k >> 6);
      const bool hi = (o < 2048);
      const int* src = Wq + (size_t)(hi ? g : g - 131072) * 64 + (k & 63);
      const int4 v = *(const int4*)src;
      const float s = scale[g];
      const float nz = -zero[g] * s;
      f32x4 b;
      if (hi) {
        b[0] = (float)((v.x >> 4) & 0xF) * s + nz;
        b[1] = (float)((v.y >> 4) & 0xF) * s + nz;
        b[2] = (float)((v.z >> 4) & 0xF) * s + nz;
        b[3] = (float)((v.w >> 4) & 0xF) * s + nz;
      } else {
        b[0] = (float)(v.x & 0xF) * s + nz;
        b[1] = (float)(v.y & 0xF) * s + nz;
        b[2] = (float)(v.z & 0xF) * s + nz;
        b[3] = (float)(v.w & 0xF) * s + nz;
      }
      *(f32x4*)&Bs[lr][lc] = b;
    }
    __syncthreads();
#pragma unroll
    for (int kk = 0; kk < 16; ++kk) {
      float a[4], b[4];
#pragma unroll
      for (int r = 0; r < 4; ++r) a[r] = As[ty * 4 + r][kk];
#pragma unroll
      for (int c = 0; c < 4; ++c) b[c] = Bs[tx * 4 + c][kk];
#pragma unroll
      for (int r = 0; r < 4; ++r)
#pragma unroll
        for (int c = 0; c < 4; ++c) acc[r][c] += a[r] * b[c];
    }
  }
#pragma unroll
  for (int r = 0; r < 4; ++r)
#pragma unroll
    for (int c = 0; c < 4; ++c) {
      const int n = n0 + tx * 4 + c;
      C[(size_t)(m0 + ty * 4 + r) * N_DIM + n] = acc[r][c] + bias[n];
    }
}

extern "C" void kernel_launch(void* const* d_in, const int* in_sizes, int n_in,
                              void* d_out, int out_size, void* d_ws, size_t ws_size,
                              hipStream_t stream) {
  const float* x     = (const float*)d_in[0];
  const int*   Wq    = (const int*)d_in[1];
  const float* scale = (const float*)d_in[2];
  const float* zero  = (const float*)d_in[3];
  const float* bias  = (const float*)d_in[4];
  float* out = (float*)d_out;

  const size_t xh_bytes = (size_t)M_DIM * K_DIM * 2;  // 64 MB
  const size_t wh_bytes = (size_t)N_DIM * K_DIM * 2;  // 32 MB

  if (ws_size >= xh_bytes + wh_bytes) {
    _Float16* xh = (_Float16*)d_ws;
    _Float16* wh = (_Float16*)((char*)d_ws + xh_bytes);
    prep<<<16384 + 8192, 256, 0, stream>>>(x, Wq, scale, zero, xh, wh);
    gemm_f16_fine<<<(M_DIM / 256) * (N_DIM / 256), 512, 0, stream>>>(xh, wh, bias, out);
  } else {
    dim3 grid(N_DIM / 64, M_DIM / 64);    // (64, 128)
    gemm_fp32_fallback<<<grid, 256, 0, stream>>>(x, Wq, scale, zero, bias, out);
  }
}